// Round 12
// baseline (121.354 us; speedup 1.0000x reference)
//
#include <hip/hip_runtime.h>

typedef unsigned short u16;
typedef unsigned int u32;
typedef unsigned long long u64;
typedef __attribute__((ext_vector_type(8))) short bf16x8;
typedef __attribute__((ext_vector_type(8))) _Float16 f16x8;
typedef __attribute__((ext_vector_type(4))) float f32x4;
typedef __attribute__((ext_vector_type(4))) u32 u32x4;

#define GLOAD16(gp, lp) __builtin_amdgcn_global_load_lds( \
  (const __attribute__((address_space(1))) unsigned int*)(gp), \
  (__attribute__((address_space(3))) unsigned int*)(lp), 16, 0, 0)

__device__ __forceinline__ u16 f2bf(float f) {
  unsigned int u = __builtin_bit_cast(unsigned int, f);
  u += 0x7fffu + ((u >> 16) & 1u);   // RNE
  return (u16)(u >> 16);
}

// packed f32x2 -> bf16x2 (bit-op RNE; compiler schedules freely)
__device__ __forceinline__ u32 pk2(float a, float b) {
  return (u32)f2bf(a) | ((u32)f2bf(b) << 16);
}

// packed f32x2 -> f16x2 via hardware v_cvt_pkrtz_f16_f32 (single op)
__device__ __forceinline__ u32 pkh(float a, float b) {
  return __builtin_bit_cast(u32, __builtin_amdgcn_cvt_pkrtz(a, b));
}

// Counted-prefetch barrier: wait for the PREVIOUS iteration's staging (its
// latency was hidden under a full iteration of compute), then raw barrier.
// sched_barrier keeps the compiler from hoisting LDS reads above it.
__device__ __forceinline__ void wait_barrier() {
  asm volatile("s_waitcnt vmcnt(0)" ::: "memory");
  __builtin_amdgcn_s_barrier();
  __builtin_amdgcn_sched_barrier(0);
}

// ---------------------------------------------------------------- converts
// One launch for x + all 4 weights: grid 8192 blocks x 1024 elems.
__global__ __launch_bounds__(256) void cvt_all(
    const float* __restrict__ x,
    const float* __restrict__ w0, const float* __restrict__ w1,
    const float* __restrict__ w2, const float* __restrict__ w3,
    u16* __restrict__ ox, u16* __restrict__ o0, u16* __restrict__ o1,
    u16* __restrict__ o2, u16* __restrict__ o3) {
  int bid = blockIdx.x;
  const float* in; u16* out; size_t off;
  if (bid < 4096) {
    in = x; out = ox; off = (size_t)bid << 10;
  } else {
    int r = bid - 4096, z = r >> 10;
    in  = (z == 0) ? w0 : (z == 1) ? w1 : (z == 2) ? w2 : w3;
    out = (z == 0) ? o0 : (z == 1) ? o1 : (z == 2) ? o2 : o3;
    off = (size_t)(r & 1023) << 10;
  }
  size_t i = off + (size_t)threadIdx.x * 4;
  float4 f = *reinterpret_cast<const float4*>(in + i);
  u64 v = (u64)pk2(f.x, f.y) | ((u64)pk2(f.z, f.w) << 32);
  *reinterpret_cast<u64*>(out + i) = v;
}

// ---------------------------------------------------------------- GEMM (B^T)
// C[m,n] = sum_k A[m,k] * Bw[n,k]; Bw:[1024,1024] bf16.
// Tile (MI*32) x 128, BK=32, 4 waves (2x2). Counted-prefetch schedule.
template<int MODE, int MI>   // MODE 0: bf16 [B,H,T,D] (scaled); 1: fp32 [M,1024]
__device__ __forceinline__ void gemm_bt_body(
    const u16* __restrict__ A, const u16* __restrict__ Bw, void* __restrict__ Cout,
    int m0, int n0, float scale) {
  const int K = 1024;
  __shared__ __align__(16) u16 As[2][MI * 32 * 32];
  __shared__ __align__(16) u16 Bs[2][128 * 32];
  const int tid = threadIdx.x;
  const int lane = tid & 63, wid = tid >> 6;
  const int wr = wid >> 1, wc = wid & 1;
  const int g = lane >> 4, c = lane & 15;
  f32x4 acc[MI][4] = {};

  auto stage = [&](int buf, int k0) {
#pragma unroll
    for (int i = 0; i < MI / 2; ++i) {
      int idx = tid + i * 256;
      int row = idx >> 2, slot = idx & 3;
      int ss = slot ^ (row & 3);
      GLOAD16(A + (size_t)(m0 + row) * K + k0 + ss * 8, &As[buf][idx * 8]);
    }
#pragma unroll
    for (int i = 0; i < 2; ++i) {
      int idx = tid + i * 256;
      int row = idx >> 2, slot = idx & 3;
      int ss = slot ^ (row & 3);
      GLOAD16(Bw + (size_t)(n0 + row) * K + k0 + ss * 8, &Bs[buf][idx * 8]);
    }
  };

  stage(0, 0);
  int buf = 0;
#pragma unroll 1
  for (int kt = 0; kt < 32; ++kt) {
    wait_barrier();
    if (kt + 1 < 32) stage(buf ^ 1, (kt + 1) * 32);
    bf16x8 af[MI], bfr[4];
#pragma unroll
    for (int mi = 0; mi < MI; ++mi) {
      int row = wr * (MI * 16) + mi * 16 + c;
      int slot = g ^ (row & 3);
      af[mi] = *(const bf16x8*)&As[buf][row * 32 + slot * 8];
    }
#pragma unroll
    for (int ni = 0; ni < 4; ++ni) {
      int row = wc * 64 + ni * 16 + c;
      int slot = g ^ (row & 3);
      bfr[ni] = *(const bf16x8*)&Bs[buf][row * 32 + slot * 8];
    }
    __builtin_amdgcn_s_setprio(1);
#pragma unroll
    for (int mi = 0; mi < MI; ++mi)
#pragma unroll
      for (int ni = 0; ni < 4; ++ni)
        acc[mi][ni] = __builtin_amdgcn_mfma_f32_16x16x32_bf16(af[mi], bfr[ni], acc[mi][ni], 0, 0, 0);
    __builtin_amdgcn_s_setprio(0);
    buf ^= 1;
  }

#pragma unroll
  for (int mi = 0; mi < MI; ++mi)
#pragma unroll
    for (int ni = 0; ni < 4; ++ni)
#pragma unroll
      for (int i = 0; i < 4; ++i) {
        int m = m0 + wr * (MI * 16) + mi * 16 + g * 4 + i;
        int n = n0 + wc * 64 + ni * 16 + c;
        float v = acc[mi][ni][i];
        if (MODE == 0) {
          int b = m >> 11, t = m & 2047, h = n >> 6, d = n & 63;
          ((u16*)Cout)[(((size_t)b * 16 + h) * 2048 + t) * 64 + d] = f2bf(v * scale);
        } else {
          ((float*)Cout)[(size_t)m * 1024 + n] = v;
        }
      }
}

// Q is pre-scaled by (1/sqrt(D)) * log2(e) so attn scores are in log2 domain.
#define QSCALE 0.1803368801111204f

__global__ __launch_bounds__(256, 3) void proj_qkv(
    const u16* __restrict__ xb, const u16* __restrict__ wq, const u16* __restrict__ wk,
    const u16* __restrict__ wv, u16* __restrict__ q, u16* __restrict__ k, u16* __restrict__ v) {
  int z = blockIdx.z;
  const u16* W = (z == 0) ? wq : (z == 1) ? wk : wv;
  u16* O = (z == 0) ? q : (z == 1) ? k : v;
  float scale = (z == 0) ? QSCALE : 1.0f;
  gemm_bt_body<0, 4>(xb, W, O, blockIdx.y * 128, blockIdx.x * 128, scale);
}

// 64-row tiles: grid (8, 64) = 512 blocks -> 2 blocks/CU.
__global__ __launch_bounds__(256, 2) void gemm_out(
    const u16* __restrict__ y, const u16* __restrict__ wp, float* __restrict__ out) {
  gemm_bt_body<1, 2>(y, wp, out, blockIdx.y * 64, blockIdx.x * 128, 1.0f);
}

// ---------------------------------------------------------------- V transpose
// v [B,H,T,64] bf16 -> vt [B,H,64,T] FP16, with per-64-tile key permutation:
// storage slot j holds real key real(j) = (2*((j>>2)&1) + (j>>5))*16
// + ((j>>3)&3)*4 + (j&3). This matches the in-register P fragment produced by
// the swapped QK^T in attn, so PV contracts correctly.
__global__ __launch_bounds__(256) void transpose_v_kernel(
    const u16* __restrict__ v, u16* __restrict__ vt) {
  __shared__ u16 tile[64][65];
  int bh = blockIdx.y, t0 = blockIdx.x * 64;
  const u16* src = v + ((size_t)bh * 2048 + t0) * 64;
  u16* dst = vt + (size_t)bh * 64 * 2048 + t0;
  int tid = threadIdx.x;
#pragma unroll
  for (int i = 0; i < 16; ++i) {
    int idx = tid + i * 256;
    tile[idx >> 6][idx & 63] = src[idx];
  }
  __syncthreads();
#pragma unroll
  for (int i = 0; i < 16; ++i) {
    int idx = tid + i * 256;
    int d = idx >> 6, j = idx & 63;
    int t = (((((j >> 2) & 1) << 1) | (j >> 5)) << 4) | (((j >> 3) & 3) << 2) | (j & 3);
    float f = __builtin_bit_cast(float, (u32)tile[t][d] << 16);
    _Float16 hh = (_Float16)f;
    dst[(size_t)d * 2048 + j] = __builtin_bit_cast(u16, hh);
  }
}

// ---------------------------------------------------------------- flash attention
// grid (32 bh, 16): 128 q-rows/block, 4 waves x 32 rows (two 16-row groups
// per wave sharing one K-tile + one V-tile LDS read -> LDS traffic per unit
// work HALVED vs 16-row waves; the LDS read pipe was the most-loaded resource).
// y-remap pairs qt {15-o, o} per CU (heavy-first, uniform per-CU sum).
// SWAPPED QK^T (mfma(K,Q)): lane (g,c) holds scores for q-row qrow0+r*16+c,
// keys ni*16+g*4+i; in-register fp16 P fragment (8 pkh per group), permuted V.
// FIXED-BASE softmax p = exp2(s) (log2-domain scores, bounded). Row-sums via
// MFMA vs all-ones. Counted-prefetch barrier at loop top.
__global__ __launch_bounds__(256, 2) void attn_kernel(
    const u16* __restrict__ q, const u16* __restrict__ kg,
    const u16* __restrict__ vt, u16* __restrict__ y) {
  const int T = 2048;
  __shared__ __align__(16) u16 Ks[2][64 * 64];   // [key][d] bf16
  __shared__ __align__(16) u16 Vs[2][64 * 64];   // [d][key-slot] fp16 (perm'd)
  const int tid = threadIdx.x, lane = tid & 63, w = tid >> 6;
  const int g = lane >> 4, c = lane & 15;
  const int bh = blockIdx.x;
  const int yy = blockIdx.y;
  const int qt = (yy < 8) ? (15 - yy) : (yy - 8);  // co-resident pair {15-o, o}
  const u16* Q = q + (size_t)bh * T * 64;
  const u16* K = kg + (size_t)bh * T * 64;
  const u16* V = vt + (size_t)bh * 64 * T;
  const int b = bh >> 4, h = bh & 15;
  const int qrow0 = qt * 128 + w * 32;   // wave owns rows qrow0 .. qrow0+31

  f16x8 ones;
#pragma unroll
  for (int j = 0; j < 8; ++j) ones[j] = (_Float16)1.0f;

  auto stage = [&](int bb, int j0) {
#pragma unroll
    for (int i = 0; i < 2; ++i) {
      int idx = tid + i * 256;
      int row = idx >> 3, slot = idx & 7;
      int ss = slot ^ (row & 7);
      GLOAD16(K + (size_t)(j0 + row) * 64 + ss * 8, &Ks[bb][idx * 8]);
      GLOAD16(V + (size_t)row * T + j0 + ss * 8, &Vs[bb][idx * 8]);
    }
  };

  bf16x8 qf[2][2];
#pragma unroll
  for (int r = 0; r < 2; ++r)
#pragma unroll
    for (int kk = 0; kk < 2; ++kk)
      qf[r][kk] = *(const bf16x8*)&Q[(size_t)(qrow0 + r * 16 + c) * 64 + kk * 32 + g * 8];

  f32x4 o[2][4] = {};
  f32x4 ol[2] = {};   // row-sums (every column identical)

  const int nkt = qt * 2 + 2;   // 64-key tiles covering keys 0 .. qt*128+127
  stage(0, 0);
  int buf = 0;
#pragma unroll 1
  for (int kt = 0; kt < nkt; ++kt) {
    const int j0 = kt * 64;
    wait_barrier();
    if (kt + 1 < nkt) stage(buf ^ 1, j0 + 64);

    // S^T = K Q^T for both row groups; kb read ONCE per wave
    bf16x8 kb[4][2];
#pragma unroll
    for (int ni = 0; ni < 4; ++ni)
#pragma unroll
      for (int kk = 0; kk < 2; ++kk) {
        int kr = ni * 16 + c;
        int slot = (kk * 4 + g) ^ (kr & 7);
        kb[ni][kk] = *(const bf16x8*)&Ks[buf][kr * 64 + slot * 8];
      }
    f32x4 s[2][4];
    __builtin_amdgcn_s_setprio(1);
#pragma unroll
    for (int r = 0; r < 2; ++r)
#pragma unroll
      for (int ni = 0; ni < 4; ++ni) {
        f32x4 a = {0.f, 0.f, 0.f, 0.f};
        a = __builtin_amdgcn_mfma_f32_16x16x32_bf16(kb[ni][0], qf[r][0], a, 0, 0, 0);
        a = __builtin_amdgcn_mfma_f32_16x16x32_bf16(kb[ni][1], qf[r][1], a, 0, 0, 0);
        s[r][ni] = a;
      }
    __builtin_amdgcn_s_setprio(0);

    // p = exp2(s); causal mask -> -inf -> 0 (only tiles near the diagonal)
    const bool dumask = (j0 + 63 > qrow0);
#pragma unroll
    for (int r = 0; r < 2; ++r)
#pragma unroll
      for (int ni = 0; ni < 4; ++ni)
#pragma unroll
        for (int i = 0; i < 4; ++i) {
          float val = s[r][ni][i];
          if (dumask) {
            int key = j0 + ni * 16 + g * 4 + i;
            if (key > qrow0 + r * 16 + c) val = -3.0e38f;
          }
          s[r][ni][i] = __builtin_amdgcn_exp2f(val);
        }

    // In-register P fragments (fp16): storage slot bb*32+g*8+qq*4+i holds
    // real key (2qq+bb)*16+g*4+i = s[r][2qq+bb][i].
    f16x8 pa[2][2];
#pragma unroll
    for (int r = 0; r < 2; ++r) {
      u32x4 p0 = { pkh(s[r][0][0], s[r][0][1]), pkh(s[r][0][2], s[r][0][3]),
                   pkh(s[r][2][0], s[r][2][1]), pkh(s[r][2][2], s[r][2][3]) };
      u32x4 p1 = { pkh(s[r][1][0], s[r][1][1]), pkh(s[r][1][2], s[r][1][3]),
                   pkh(s[r][3][0], s[r][3][1]), pkh(s[r][3][2], s[r][3][3]) };
      pa[r][0] = __builtin_bit_cast(f16x8, p0);
      pa[r][1] = __builtin_bit_cast(f16x8, p1);
    }

    // O += P @ V; l += P @ 1; vb read ONCE per wave, used by both groups
    f16x8 vb[4][2];
#pragma unroll
    for (int di = 0; di < 4; ++di)
#pragma unroll
      for (int kk = 0; kk < 2; ++kk) {
        int d = di * 16 + c;
        int slot = (kk * 4 + g) ^ (d & 7);
        vb[di][kk] = *(const f16x8*)&Vs[buf][d * 64 + slot * 8];
      }
    __builtin_amdgcn_s_setprio(1);
#pragma unroll
    for (int r = 0; r < 2; ++r) {
      ol[r] = __builtin_amdgcn_mfma_f32_16x16x32_f16(pa[r][0], ones, ol[r], 0, 0, 0);
      ol[r] = __builtin_amdgcn_mfma_f32_16x16x32_f16(pa[r][1], ones, ol[r], 0, 0, 0);
    }
#pragma unroll
    for (int di = 0; di < 4; ++di)
#pragma unroll
      for (int r = 0; r < 2; ++r) {
        o[r][di] = __builtin_amdgcn_mfma_f32_16x16x32_f16(pa[r][0], vb[di][0], o[r][di], 0, 0, 0);
        o[r][di] = __builtin_amdgcn_mfma_f32_16x16x32_f16(pa[r][1], vb[di][1], o[r][di], 0, 0, 0);
      }
    __builtin_amdgcn_s_setprio(0);
    buf ^= 1;
  }

  // epilogue: y[b, t, h*64 + d] = o / l   (o rows = q-rows r*16+g*4+i)
#pragma unroll
  for (int r = 0; r < 2; ++r)
#pragma unroll
    for (int i = 0; i < 4; ++i) {
      float inv = 1.f / ol[r][i];
      int t = qrow0 + r * 16 + g * 4 + i;
#pragma unroll
      for (int di = 0; di < 4; ++di) {
        int col = h * 64 + di * 16 + c;
        y[((size_t)b * 2048 + t) * 1024 + col] = f2bf(o[r][di][i] * inv);
      }
    }
}

// ---------------------------------------------------------------- launch
extern "C" void kernel_launch(void* const* d_in, const int* in_sizes, int n_in,
                              void* d_out, int out_size, void* d_ws, size_t ws_size,
                              hipStream_t stream) {
  // setup_inputs order: x, Wk, Wq, Wv, Wp
  const float* x  = (const float*)d_in[0];
  const float* Wk = (const float*)d_in[1];
  const float* Wq = (const float*)d_in[2];
  const float* Wv = (const float*)d_in[3];
  const float* Wp = (const float*)d_in[4];
  float* out = (float*)d_out;

  char* ws = (char*)d_ws;
  const size_t SZ_X = (size_t)4096 * 1024 * 2;  // 8 MiB (x_bf16 / q / k / v each)
  const size_t SZ_W = (size_t)1024 * 1024 * 2;  // 2 MiB per weight
  u16* xb  = (u16*)(ws);                  // x bf16; reused as vt (fp16) after proj
  u16* qb  = (u16*)(ws + SZ_X);
  u16* kb  = (u16*)(ws + 2 * SZ_X);
  u16* vb  = (u16*)(ws + 3 * SZ_X);       // v [B,H,T,D]; reused as y after transpose
  u16* wqb = (u16*)(ws + 4 * SZ_X);
  u16* wkb = (u16*)(ws + 4 * SZ_X + SZ_W);
  u16* wvb = (u16*)(ws + 4 * SZ_X + 2 * SZ_W);
  u16* wpb = (u16*)(ws + 4 * SZ_X + 3 * SZ_W);
  // total workspace: 40 MiB

  cvt_all<<<8192, 256, 0, stream>>>(x, Wq, Wk, Wv, Wp, xb, wqb, wkb, wvb, wpb);

  proj_qkv<<<dim3(8, 32, 3), 256, 0, stream>>>(xb, wqb, wkb, wvb, qb, kb, vb);

  u16* vtb = xb;  // x_bf16 is dead after projections
  transpose_v_kernel<<<dim3(32, 32), 256, 0, stream>>>(vb, vtb);

  u16* yb = vb;   // v [B,H,T,D] is dead after transpose
  attn_kernel<<<dim3(32, 16), 256, 0, stream>>>(qb, kb, vtb, yb);

  gemm_out<<<dim3(8, 64), 256, 0, stream>>>(yb, wpb, out);
}

// Round 13
// 119.329 us; speedup vs baseline: 1.0170x; 1.0170x over previous
//
#include <hip/hip_runtime.h>

typedef unsigned short u16;
typedef unsigned int u32;
typedef unsigned long long u64;
typedef __attribute__((ext_vector_type(8))) short bf16x8;
typedef __attribute__((ext_vector_type(8))) _Float16 f16x8;
typedef __attribute__((ext_vector_type(4))) float f32x4;
typedef __attribute__((ext_vector_type(4))) u32 u32x4;

#define GLOAD16(gp, lp) __builtin_amdgcn_global_load_lds( \
  (const __attribute__((address_space(1))) unsigned int*)(gp), \
  (__attribute__((address_space(3))) unsigned int*)(lp), 16, 0, 0)

__device__ __forceinline__ u16 f2bf(float f) {
  unsigned int u = __builtin_bit_cast(unsigned int, f);
  u += 0x7fffu + ((u >> 16) & 1u);   // RNE
  return (u16)(u >> 16);
}

// packed f32x2 -> bf16x2 (bit-op RNE; compiler schedules freely)
__device__ __forceinline__ u32 pk2(float a, float b) {
  return (u32)f2bf(a) | ((u32)f2bf(b) << 16);
}

// packed f32x2 -> f16x2 via hardware v_cvt_pkrtz_f16_f32 (single op)
__device__ __forceinline__ u32 pkh(float a, float b) {
  return __builtin_bit_cast(u32, __builtin_amdgcn_cvt_pkrtz(a, b));
}

// Counted-prefetch barrier: wait for the PREVIOUS iteration's staging (its
// latency was hidden under a full iteration of compute), then raw barrier.
// sched_barrier keeps the compiler from hoisting LDS reads above it.
__device__ __forceinline__ void wait_barrier() {
  asm volatile("s_waitcnt vmcnt(0)" ::: "memory");
  __builtin_amdgcn_s_barrier();
  __builtin_amdgcn_sched_barrier(0);
}

// ---------------------------------------------------------------- converts
// One launch for x + all 4 weights: grid 8192 blocks x 1024 elems.
__global__ __launch_bounds__(256) void cvt_all(
    const float* __restrict__ x,
    const float* __restrict__ w0, const float* __restrict__ w1,
    const float* __restrict__ w2, const float* __restrict__ w3,
    u16* __restrict__ ox, u16* __restrict__ o0, u16* __restrict__ o1,
    u16* __restrict__ o2, u16* __restrict__ o3) {
  int bid = blockIdx.x;
  const float* in; u16* out; size_t off;
  if (bid < 4096) {
    in = x; out = ox; off = (size_t)bid << 10;
  } else {
    int r = bid - 4096, z = r >> 10;
    in  = (z == 0) ? w0 : (z == 1) ? w1 : (z == 2) ? w2 : w3;
    out = (z == 0) ? o0 : (z == 1) ? o1 : (z == 2) ? o2 : o3;
    off = (size_t)(r & 1023) << 10;
  }
  size_t i = off + (size_t)threadIdx.x * 4;
  float4 f = *reinterpret_cast<const float4*>(in + i);
  u64 v = (u64)pk2(f.x, f.y) | ((u64)pk2(f.z, f.w) << 32);
  *reinterpret_cast<u64*>(out + i) = v;
}

// ---------------------------------------------------------------- GEMM (B^T)
// C[m,n] = sum_k A[m,k] * Bw[n,k]; Bw:[1024,1024] bf16.
// Tile (MI*32) x 128, BK=32, 4 waves (2x2). Counted-prefetch schedule.
// MODE 0: bf16 [B,H,T,D] (scaled) -- q, k
// MODE 1: fp32 row-major [M,1024] -- final output
// MODE 2: fp16 [B,H,64,T] transposed V with key permutation (slot j holds
//         real key real(j)); j = inv(t&63) with inv the exact bit-inverse of
//         real(j) = (2*((j>>2)&1)+(j>>5))*16 + ((j>>3)&3)*4 + (j&3).
template<int MODE, int MI>
__device__ __forceinline__ void gemm_bt_body(
    const u16* __restrict__ A, const u16* __restrict__ Bw, void* __restrict__ Cout,
    int m0, int n0, float scale) {
  const int K = 1024;
  __shared__ __align__(16) u16 As[2][MI * 32 * 32];
  __shared__ __align__(16) u16 Bs[2][128 * 32];
  const int tid = threadIdx.x;
  const int lane = tid & 63, wid = tid >> 6;
  const int wr = wid >> 1, wc = wid & 1;
  const int g = lane >> 4, c = lane & 15;
  f32x4 acc[MI][4] = {};

  auto stage = [&](int buf, int k0) {
#pragma unroll
    for (int i = 0; i < MI / 2; ++i) {
      int idx = tid + i * 256;
      int row = idx >> 2, slot = idx & 3;
      int ss = slot ^ (row & 3);
      GLOAD16(A + (size_t)(m0 + row) * K + k0 + ss * 8, &As[buf][idx * 8]);
    }
#pragma unroll
    for (int i = 0; i < 2; ++i) {
      int idx = tid + i * 256;
      int row = idx >> 2, slot = idx & 3;
      int ss = slot ^ (row & 3);
      GLOAD16(Bw + (size_t)(n0 + row) * K + k0 + ss * 8, &Bs[buf][idx * 8]);
    }
  };

  stage(0, 0);
  int buf = 0;
#pragma unroll 1
  for (int kt = 0; kt < 32; ++kt) {
    wait_barrier();
    if (kt + 1 < 32) stage(buf ^ 1, (kt + 1) * 32);
    bf16x8 af[MI], bfr[4];
#pragma unroll
    for (int mi = 0; mi < MI; ++mi) {
      int row = wr * (MI * 16) + mi * 16 + c;
      int slot = g ^ (row & 3);
      af[mi] = *(const bf16x8*)&As[buf][row * 32 + slot * 8];
    }
#pragma unroll
    for (int ni = 0; ni < 4; ++ni) {
      int row = wc * 64 + ni * 16 + c;
      int slot = g ^ (row & 3);
      bfr[ni] = *(const bf16x8*)&Bs[buf][row * 32 + slot * 8];
    }
    __builtin_amdgcn_s_setprio(1);
#pragma unroll
    for (int mi = 0; mi < MI; ++mi)
#pragma unroll
      for (int ni = 0; ni < 4; ++ni)
        acc[mi][ni] = __builtin_amdgcn_mfma_f32_16x16x32_bf16(af[mi], bfr[ni], acc[mi][ni], 0, 0, 0);
    __builtin_amdgcn_s_setprio(0);
    buf ^= 1;
  }

#pragma unroll
  for (int mi = 0; mi < MI; ++mi)
#pragma unroll
    for (int ni = 0; ni < 4; ++ni)
#pragma unroll
      for (int i = 0; i < 4; ++i) {
        int m = m0 + wr * (MI * 16) + mi * 16 + g * 4 + i;
        int n = n0 + wc * 64 + ni * 16 + c;
        float v = acc[mi][ni][i];
        if (MODE == 0) {
          int b = m >> 11, t = m & 2047, h = n >> 6, d = n & 63;
          ((u16*)Cout)[(((size_t)b * 16 + h) * 2048 + t) * 64 + d] = f2bf(v * scale);
        } else if (MODE == 1) {
          ((float*)Cout)[(size_t)m * 1024 + n] = v;
        } else {
          int b = m >> 11, t = m & 2047, h = n >> 6, d = n & 63;
          int t0 = t & ~63, k = t & 63;
          int j = (((k >> 4) & 1) << 5) | (((k >> 3) & 1) << 4) | (((k >> 2) & 1) << 3)
                | (((k >> 5) & 1) << 2) | (k & 3);
          _Float16 hh = (_Float16)v;
          ((u16*)Cout)[(((size_t)b * 16 + h) * 64 + d) * 2048 + t0 + j] =
              __builtin_bit_cast(u16, hh);
        }
      }
}

// Q is pre-scaled by (1/sqrt(D)) * log2(e) so attn scores are in log2 domain.
#define QSCALE 0.1803368801111204f

__global__ __launch_bounds__(256, 3) void proj_qkv(
    const u16* __restrict__ xb, const u16* __restrict__ wq, const u16* __restrict__ wk,
    const u16* __restrict__ wv, u16* __restrict__ q, u16* __restrict__ k, u16* __restrict__ vt) {
  int z = blockIdx.z;
  if (z == 2) {
    // V: fused transpose + fp16 + key permutation
    gemm_bt_body<2, 4>(xb, wv, vt, blockIdx.y * 128, blockIdx.x * 128, 1.0f);
  } else {
    const u16* W = (z == 0) ? wq : wk;
    u16* O = (z == 0) ? q : k;
    float scale = (z == 0) ? QSCALE : 1.0f;
    gemm_bt_body<0, 4>(xb, W, O, blockIdx.y * 128, blockIdx.x * 128, scale);
  }
}

// 64-row tiles: grid (8, 64) = 512 blocks -> 2 blocks/CU.
__global__ __launch_bounds__(256, 2) void gemm_out(
    const u16* __restrict__ y, const u16* __restrict__ wp, float* __restrict__ out) {
  gemm_bt_body<1, 2>(y, wp, out, blockIdx.y * 64, blockIdx.x * 128, 1.0f);
}

// ---------------------------------------------------------------- flash attention
// grid (32 bh, 32): 64 q-rows/block (4 waves x 16), KVBLK=64, 32KB LDS,
// 4 blocks/CU. qt remap balances per-CU work: co-resident blocks (linear ids
// differing by 256 -> same CU) have y in {o,o+8,o+16,o+24}; qt(y) =
// {o, 31-o, 8+o, 23-o} makes every CU's iteration sum exactly 66.
// SWAPPED QK^T: mfma(K,Q) -> lane (g,c) holds 16 scores for q-row (qrow0+c),
// keys ni*16+g*4+i. With the matching V storage permutation, the PV A-frag
// is packed fully IN REGISTERS (8 pkh) -> no P LDS round-trip at all.
// FIXED-BASE softmax: p = exp2(s) directly (log2-domain scores, bounded;
// fp32 exp2 headroom ~2^116). Row-sums via MFMA vs all-ones. Counted-prefetch
// barrier at loop top hides staging latency under a full iteration.
__global__ __launch_bounds__(256, 4) void attn_kernel(
    const u16* __restrict__ q, const u16* __restrict__ kg,
    const u16* __restrict__ vt, u16* __restrict__ y) {
  const int T = 2048;
  __shared__ __align__(16) u16 Ks[2][64 * 64];   // [key][d] bf16
  __shared__ __align__(16) u16 Vs[2][64 * 64];   // [d][key-slot] fp16 (perm'd)
  const int tid = threadIdx.x, lane = tid & 63, w = tid >> 6;
  const int g = lane >> 4, c = lane & 15;
  const int bh = blockIdx.x;
  const int yy = blockIdx.y, m8 = yy >> 3, o8 = yy & 7;
  const int qt = (m8 == 0) ? o8 : (m8 == 1) ? 31 - o8 : (m8 == 2) ? 8 + o8 : 23 - o8;
  const u16* Q = q + (size_t)bh * T * 64;
  const u16* K = kg + (size_t)bh * T * 64;
  const u16* V = vt + (size_t)bh * 64 * T;
  const int b = bh >> 4, h = bh & 15;
  const int qrow0 = qt * 64 + w * 16;

  f16x8 ones;
#pragma unroll
  for (int j = 0; j < 8; ++j) ones[j] = (_Float16)1.0f;

  auto stage = [&](int bb, int j0) {
#pragma unroll
    for (int i = 0; i < 2; ++i) {
      int idx = tid + i * 256;
      int row = idx >> 3, slot = idx & 7;
      int ss = slot ^ (row & 7);
      GLOAD16(K + (size_t)(j0 + row) * 64 + ss * 8, &Ks[bb][idx * 8]);
      GLOAD16(V + (size_t)row * T + j0 + ss * 8, &Vs[bb][idx * 8]);
    }
  };

  bf16x8 qf[2];
#pragma unroll
  for (int kk = 0; kk < 2; ++kk)
    qf[kk] = *(const bf16x8*)&Q[(size_t)(qrow0 + c) * 64 + kk * 32 + g * 8];

  f32x4 o[4] = {};
  f32x4 ol = {};   // row-sums (every column identical)

  const int nkt = qt + 1;
  stage(0, 0);
  int buf = 0;
#pragma unroll 1
  for (int kt = 0; kt < nkt; ++kt) {
    const int j0 = kt * 64;
    wait_barrier();
    if (kt + 1 < nkt) stage(buf ^ 1, j0 + 64);

    // S^T = K Q^T: s[ni][i] = S[q-row qrow0+c][key j0 + ni*16 + g*4 + i]
    bf16x8 kb[4][2];
#pragma unroll
    for (int ni = 0; ni < 4; ++ni)
#pragma unroll
      for (int kk = 0; kk < 2; ++kk) {
        int kr = ni * 16 + c;
        int slot = (kk * 4 + g) ^ (kr & 7);
        kb[ni][kk] = *(const bf16x8*)&Ks[buf][kr * 64 + slot * 8];
      }
    f32x4 s[4];
    __builtin_amdgcn_s_setprio(1);
#pragma unroll
    for (int ni = 0; ni < 4; ++ni) {
      f32x4 a = {0.f, 0.f, 0.f, 0.f};
      a = __builtin_amdgcn_mfma_f32_16x16x32_bf16(kb[ni][0], qf[0], a, 0, 0, 0);
      a = __builtin_amdgcn_mfma_f32_16x16x32_bf16(kb[ni][1], qf[1], a, 0, 0, 0);
      s[ni] = a;
    }
    __builtin_amdgcn_s_setprio(0);

    // p = exp2(s); causal mask -> -inf -> 0 (only diag tile masks)
    const bool dumask = (kt == qt);
#pragma unroll
    for (int ni = 0; ni < 4; ++ni)
#pragma unroll
      for (int i = 0; i < 4; ++i) {
        float val = s[ni][i];
        if (dumask) {
          int key = j0 + ni * 16 + g * 4 + i;
          if (key > qrow0 + c) val = -3.0e38f;
        }
        s[ni][i] = __builtin_amdgcn_exp2f(val);
      }

    // In-register P fragment (fp16): storage slot b*32+g*8+q*4+i holds real
    // key (2q+b)*16+g*4+i = s[2q+b][i]. Matches V's storage permutation.
    u32x4 pa0 = { pkh(s[0][0], s[0][1]), pkh(s[0][2], s[0][3]),
                  pkh(s[2][0], s[2][1]), pkh(s[2][2], s[2][3]) };
    u32x4 pa1 = { pkh(s[1][0], s[1][1]), pkh(s[1][2], s[1][3]),
                  pkh(s[3][0], s[3][1]), pkh(s[3][2], s[3][3]) };
    f16x8 pa[2];
    pa[0] = __builtin_bit_cast(f16x8, pa0);
    pa[1] = __builtin_bit_cast(f16x8, pa1);

    // O += P @ V; l += P @ 1 (fp16 inputs, fp32 accum)
    f16x8 vb[4][2];
#pragma unroll
    for (int di = 0; di < 4; ++di)
#pragma unroll
      for (int kk = 0; kk < 2; ++kk) {
        int d = di * 16 + c;
        int slot = (kk * 4 + g) ^ (d & 7);
        vb[di][kk] = *(const f16x8*)&Vs[buf][d * 64 + slot * 8];
      }
    __builtin_amdgcn_s_setprio(1);
    ol = __builtin_amdgcn_mfma_f32_16x16x32_f16(pa[0], ones, ol, 0, 0, 0);
    ol = __builtin_amdgcn_mfma_f32_16x16x32_f16(pa[1], ones, ol, 0, 0, 0);
#pragma unroll
    for (int di = 0; di < 4; ++di) {
      o[di] = __builtin_amdgcn_mfma_f32_16x16x32_f16(pa[0], vb[di][0], o[di], 0, 0, 0);
      o[di] = __builtin_amdgcn_mfma_f32_16x16x32_f16(pa[1], vb[di][1], o[di], 0, 0, 0);
    }
    __builtin_amdgcn_s_setprio(0);
    buf ^= 1;
  }

  // epilogue: y[b, t, h*64 + d] = o / l   (o rows = q-rows g*4+i, cols = d)
#pragma unroll
  for (int i = 0; i < 4; ++i) {
    float inv = 1.f / ol[i];
    int t = qrow0 + g * 4 + i;
#pragma unroll
    for (int di = 0; di < 4; ++di) {
      int col = h * 64 + di * 16 + c;
      y[((size_t)b * 2048 + t) * 1024 + col] = f2bf(o[di][i] * inv);
    }
  }
}

// ---------------------------------------------------------------- launch
extern "C" void kernel_launch(void* const* d_in, const int* in_sizes, int n_in,
                              void* d_out, int out_size, void* d_ws, size_t ws_size,
                              hipStream_t stream) {
  // setup_inputs order: x, Wk, Wq, Wv, Wp
  const float* x  = (const float*)d_in[0];
  const float* Wk = (const float*)d_in[1];
  const float* Wq = (const float*)d_in[2];
  const float* Wv = (const float*)d_in[3];
  const float* Wp = (const float*)d_in[4];
  float* out = (float*)d_out;

  char* ws = (char*)d_ws;
  const size_t SZ_X = (size_t)4096 * 1024 * 2;  // 8 MiB per activation buffer
  const size_t SZ_W = (size_t)1024 * 1024 * 2;  // 2 MiB per weight
  u16* xb  = (u16*)(ws);                  // x bf16; reused as y after proj
  u16* qb  = (u16*)(ws + SZ_X);
  u16* kb  = (u16*)(ws + 2 * SZ_X);
  u16* vtb = (u16*)(ws + 3 * SZ_X);       // V^T fp16 [B,H,64,T], written by proj
  u16* wqb = (u16*)(ws + 4 * SZ_X);
  u16* wkb = (u16*)(ws + 4 * SZ_X + SZ_W);
  u16* wvb = (u16*)(ws + 4 * SZ_X + 2 * SZ_W);
  u16* wpb = (u16*)(ws + 4 * SZ_X + 3 * SZ_W);
  // total workspace: 40 MiB

  cvt_all<<<8192, 256, 0, stream>>>(x, Wq, Wk, Wv, Wp, xb, wqb, wkb, wvb, wpb);

  proj_qkv<<<dim3(8, 32, 3), 256, 0, stream>>>(xb, wqb, wkb, wvb, qb, kb, vtb);

  u16* yb = xb;   // x_bf16 is dead after projections
  attn_kernel<<<dim3(32, 32), 256, 0, stream>>>(qb, kb, vtb, yb);

  gemm_out<<<dim3(8, 64), 256, 0, stream>>>(yb, wpb, out);
}

// Round 14
// 117.072 us; speedup vs baseline: 1.0366x; 1.0193x over previous
//
#include <hip/hip_runtime.h>

typedef unsigned short u16;
typedef unsigned int u32;
typedef unsigned long long u64;
typedef __attribute__((ext_vector_type(8))) short bf16x8;
typedef __attribute__((ext_vector_type(8))) _Float16 f16x8;
typedef __attribute__((ext_vector_type(4))) float f32x4;
typedef __attribute__((ext_vector_type(4))) u32 u32x4;

#define GLOAD16(gp, lp) __builtin_amdgcn_global_load_lds( \
  (const __attribute__((address_space(1))) unsigned int*)(gp), \
  (__attribute__((address_space(3))) unsigned int*)(lp), 16, 0, 0)

__device__ __forceinline__ u16 f2bf(float f) {
  unsigned int u = __builtin_bit_cast(unsigned int, f);
  u += 0x7fffu + ((u >> 16) & 1u);   // RNE
  return (u16)(u >> 16);
}

// packed f32x2 -> bf16x2 (bit-op RNE; compiler schedules freely)
__device__ __forceinline__ u32 pk2(float a, float b) {
  return (u32)f2bf(a) | ((u32)f2bf(b) << 16);
}

// packed f32x2 -> f16x2 via hardware v_cvt_pkrtz_f16_f32 (single op)
__device__ __forceinline__ u32 pkh(float a, float b) {
  return __builtin_bit_cast(u32, __builtin_amdgcn_cvt_pkrtz(a, b));
}

// Counted-prefetch barrier: wait for the PREVIOUS iteration's staging (its
// latency was hidden under a full iteration of compute), then raw barrier.
// sched_barrier keeps the compiler from hoisting LDS reads above it.
__device__ __forceinline__ void wait_barrier() {
  asm volatile("s_waitcnt vmcnt(0)" ::: "memory");
  __builtin_amdgcn_s_barrier();
  __builtin_amdgcn_sched_barrier(0);
}

// ---------------------------------------------------------------- converts
// Weights only (x is consumed as fp32 directly by proj): grid (1024, 4).
__global__ __launch_bounds__(256) void cvt_w4(
    const float* __restrict__ w0, const float* __restrict__ w1,
    const float* __restrict__ w2, const float* __restrict__ w3,
    u16* __restrict__ o0, u16* __restrict__ o1,
    u16* __restrict__ o2, u16* __restrict__ o3) {
  int z = blockIdx.y;
  const float* in = (z == 0) ? w0 : (z == 1) ? w1 : (z == 2) ? w2 : w3;
  u16* out = (z == 0) ? o0 : (z == 1) ? o1 : (z == 2) ? o2 : o3;
  int i = (blockIdx.x * 256 + threadIdx.x) * 4;
  float4 f = *reinterpret_cast<const float4*>(in + i);
  u64 v = (u64)pk2(f.x, f.y) | ((u64)pk2(f.z, f.w) << 32);
  *reinterpret_cast<u64*>(out + i) = v;
}

// ---------------------------------------------------------------- GEMM (B^T)
// C[m,n] = sum_k A[m,k] * Bw[n,k]; Bw:[1024,1024] bf16.
// Tile (MI*32) x 128, BK=32, 4 waves (2x2). Counted-prefetch schedule.
// AF32=1: A staged as fp32 from global (linear LDS dest, inverse-swizzled
// source), fragments converted to bf16 in-register with RNE (same numerics
// as a pre-converted bf16 A).
template<int MODE, int MI, int AF32>   // MODE 0: bf16 [B,H,T,D]; 1: fp32 [M,1024]
__device__ __forceinline__ void gemm_bt_body(
    const void* __restrict__ Av, const u16* __restrict__ Bw, void* __restrict__ Cout,
    int m0, int n0, float scale) {
  const int K = 1024;
  __shared__ __align__(16) u16 As[2][MI * 32 * 32 * (AF32 ? 2 : 1)];
  __shared__ __align__(16) u16 Bs[2][128 * 32];
  const int tid = threadIdx.x;
  const int lane = tid & 63, wid = tid >> 6;
  const int wr = wid >> 1, wc = wid & 1;
  const int g = lane >> 4, c = lane & 15;
  f32x4 acc[MI][4] = {};

  auto stage = [&](int buf, int k0) {
    if (AF32) {
      const float* A = (const float*)Av;
#pragma unroll
      for (int i = 0; i < MI; ++i) {        // MI*256 chunks of 4 floats
        int idx = tid + i * 256;
        int row = idx >> 3, slot = idx & 7;
        int ss = slot ^ (row & 7);
        GLOAD16(A + (size_t)(m0 + row) * K + k0 + ss * 4,
                ((float*)&As[buf][0]) + idx * 4);
      }
    } else {
      const u16* A = (const u16*)Av;
#pragma unroll
      for (int i = 0; i < MI / 2; ++i) {
        int idx = tid + i * 256;
        int row = idx >> 2, slot = idx & 3;
        int ss = slot ^ (row & 3);
        GLOAD16(A + (size_t)(m0 + row) * K + k0 + ss * 8, &As[buf][idx * 8]);
      }
    }
#pragma unroll
    for (int i = 0; i < 2; ++i) {
      int idx = tid + i * 256;
      int row = idx >> 2, slot = idx & 3;
      int ss = slot ^ (row & 3);
      GLOAD16(Bw + (size_t)(n0 + row) * K + k0 + ss * 8, &Bs[buf][idx * 8]);
    }
  };

  stage(0, 0);
  int buf = 0;
#pragma unroll 1
  for (int kt = 0; kt < 32; ++kt) {
    wait_barrier();
    if (kt + 1 < 32) stage(buf ^ 1, (kt + 1) * 32);
    bf16x8 af[MI], bfr[4];
#pragma unroll
    for (int mi = 0; mi < MI; ++mi) {
      int row = wr * (MI * 16) + mi * 16 + c;
      if (AF32) {
        const float* Ab = (const float*)&As[buf][0];
        int s0 = (g * 2) ^ (row & 7);
        int s1 = (g * 2 + 1) ^ (row & 7);
        f32x4 lo = *(const f32x4*)(Ab + row * 32 + s0 * 4);
        f32x4 hi = *(const f32x4*)(Ab + row * 32 + s1 * 4);
        u32x4 p = { pk2(lo[0], lo[1]), pk2(lo[2], lo[3]),
                    pk2(hi[0], hi[1]), pk2(hi[2], hi[3]) };
        af[mi] = __builtin_bit_cast(bf16x8, p);
      } else {
        int slot = g ^ (row & 3);
        af[mi] = *(const bf16x8*)&As[buf][row * 32 + slot * 8];
      }
    }
#pragma unroll
    for (int ni = 0; ni < 4; ++ni) {
      int row = wc * 64 + ni * 16 + c;
      int slot = g ^ (row & 3);
      bfr[ni] = *(const bf16x8*)&Bs[buf][row * 32 + slot * 8];
    }
    __builtin_amdgcn_s_setprio(1);
#pragma unroll
    for (int mi = 0; mi < MI; ++mi)
#pragma unroll
      for (int ni = 0; ni < 4; ++ni)
        acc[mi][ni] = __builtin_amdgcn_mfma_f32_16x16x32_bf16(af[mi], bfr[ni], acc[mi][ni], 0, 0, 0);
    __builtin_amdgcn_s_setprio(0);
    buf ^= 1;
  }

#pragma unroll
  for (int mi = 0; mi < MI; ++mi)
#pragma unroll
    for (int ni = 0; ni < 4; ++ni)
#pragma unroll
      for (int i = 0; i < 4; ++i) {
        int m = m0 + wr * (MI * 16) + mi * 16 + g * 4 + i;
        int n = n0 + wc * 64 + ni * 16 + c;
        float v = acc[mi][ni][i];
        if (MODE == 0) {
          int b = m >> 11, t = m & 2047, h = n >> 6, d = n & 63;
          ((u16*)Cout)[(((size_t)b * 16 + h) * 2048 + t) * 64 + d] = f2bf(v * scale);
        } else {
          ((float*)Cout)[(size_t)m * 1024 + n] = v;
        }
      }
}

// Q is pre-scaled by (1/sqrt(D)) * log2(e) so attn scores are in log2 domain.
#define QSCALE 0.1803368801111204f

__global__ __launch_bounds__(256, 3) void proj_qkv(
    const float* __restrict__ x, const u16* __restrict__ wq, const u16* __restrict__ wk,
    const u16* __restrict__ wv, u16* __restrict__ q, u16* __restrict__ k, u16* __restrict__ v) {
  int z = blockIdx.z;
  const u16* W = (z == 0) ? wq : (z == 1) ? wk : wv;
  u16* O = (z == 0) ? q : (z == 1) ? k : v;
  float scale = (z == 0) ? QSCALE : 1.0f;
  gemm_bt_body<0, 4, 1>(x, W, O, blockIdx.y * 128, blockIdx.x * 128, scale);
}

// 64-row tiles: grid (8, 64) = 512 blocks -> 2 blocks/CU.
__global__ __launch_bounds__(256, 2) void gemm_out(
    const u16* __restrict__ y, const u16* __restrict__ wp, float* __restrict__ out) {
  gemm_bt_body<1, 2, 0>(y, wp, out, blockIdx.y * 64, blockIdx.x * 128, 1.0f);
}

// ---------------------------------------------------------------- V transpose
// v [B,H,T,64] bf16 -> vt [B,H,64,T] FP16, with per-64-tile key permutation:
// storage slot j holds real key real(j) = (2*((j>>2)&1) + (j>>5))*16
// + ((j>>3)&3)*4 + (j&3). This matches the in-register P fragment produced by
// the swapped QK^T in attn, so PV contracts correctly.
__global__ __launch_bounds__(256) void transpose_v_kernel(
    const u16* __restrict__ v, u16* __restrict__ vt) {
  __shared__ u16 tile[64][65];
  int bh = blockIdx.y, t0 = blockIdx.x * 64;
  const u16* src = v + ((size_t)bh * 2048 + t0) * 64;
  u16* dst = vt + (size_t)bh * 64 * 2048 + t0;
  int tid = threadIdx.x;
#pragma unroll
  for (int i = 0; i < 16; ++i) {
    int idx = tid + i * 256;
    tile[idx >> 6][idx & 63] = src[idx];
  }
  __syncthreads();
#pragma unroll
  for (int i = 0; i < 16; ++i) {
    int idx = tid + i * 256;
    int d = idx >> 6, j = idx & 63;
    int t = (((((j >> 2) & 1) << 1) | (j >> 5)) << 4) | (((j >> 3) & 3) << 2) | (j & 3);
    float f = __builtin_bit_cast(float, (u32)tile[t][d] << 16);
    _Float16 hh = (_Float16)f;
    dst[(size_t)d * 2048 + j] = __builtin_bit_cast(u16, hh);
  }
}

// ---------------------------------------------------------------- flash attention
// grid (32 bh, 32): 64 q-rows/block (4 waves x 16), KVBLK=64, 32KB LDS,
// 4 blocks/CU. qt remap balances per-CU work: co-resident blocks (linear ids
// differing by 256 -> same CU) have y in {o,o+8,o+16,o+24}; qt(y) =
// {o, 31-o, 8+o, 23-o} makes every CU's iteration sum exactly 66.
// SWAPPED QK^T: mfma(K,Q) -> lane (g,c) holds 16 scores for q-row (qrow0+c),
// keys ni*16+g*4+i. With the matching V storage permutation, the PV A-frag
// is packed fully IN REGISTERS (8 pkh) -> no P LDS round-trip at all.
// FIXED-BASE softmax: p = exp2(s) directly (log2-domain scores, bounded;
// fp32 exp2 headroom ~2^116). Row-sums via MFMA vs all-ones. Counted-prefetch
// barrier at loop top hides staging latency under a full iteration.
__global__ __launch_bounds__(256, 4) void attn_kernel(
    const u16* __restrict__ q, const u16* __restrict__ kg,
    const u16* __restrict__ vt, u16* __restrict__ y) {
  const int T = 2048;
  __shared__ __align__(16) u16 Ks[2][64 * 64];   // [key][d] bf16
  __shared__ __align__(16) u16 Vs[2][64 * 64];   // [d][key-slot] fp16 (perm'd)
  const int tid = threadIdx.x, lane = tid & 63, w = tid >> 6;
  const int g = lane >> 4, c = lane & 15;
  const int bh = blockIdx.x;
  const int yy = blockIdx.y, m8 = yy >> 3, o8 = yy & 7;
  const int qt = (m8 == 0) ? o8 : (m8 == 1) ? 31 - o8 : (m8 == 2) ? 8 + o8 : 23 - o8;
  const u16* Q = q + (size_t)bh * T * 64;
  const u16* K = kg + (size_t)bh * T * 64;
  const u16* V = vt + (size_t)bh * 64 * T;
  const int b = bh >> 4, h = bh & 15;
  const int qrow0 = qt * 64 + w * 16;

  f16x8 ones;
#pragma unroll
  for (int j = 0; j < 8; ++j) ones[j] = (_Float16)1.0f;

  auto stage = [&](int bb, int j0) {
#pragma unroll
    for (int i = 0; i < 2; ++i) {
      int idx = tid + i * 256;
      int row = idx >> 3, slot = idx & 7;
      int ss = slot ^ (row & 7);
      GLOAD16(K + (size_t)(j0 + row) * 64 + ss * 8, &Ks[bb][idx * 8]);
      GLOAD16(V + (size_t)row * T + j0 + ss * 8, &Vs[bb][idx * 8]);
    }
  };

  bf16x8 qf[2];
#pragma unroll
  for (int kk = 0; kk < 2; ++kk)
    qf[kk] = *(const bf16x8*)&Q[(size_t)(qrow0 + c) * 64 + kk * 32 + g * 8];

  f32x4 o[4] = {};
  f32x4 ol = {};   // row-sums (every column identical)

  const int nkt = qt + 1;
  stage(0, 0);
  int buf = 0;
#pragma unroll 1
  for (int kt = 0; kt < nkt; ++kt) {
    const int j0 = kt * 64;
    wait_barrier();
    if (kt + 1 < nkt) stage(buf ^ 1, j0 + 64);

    // S^T = K Q^T: s[ni][i] = S[q-row qrow0+c][key j0 + ni*16 + g*4 + i]
    bf16x8 kb[4][2];
#pragma unroll
    for (int ni = 0; ni < 4; ++ni)
#pragma unroll
      for (int kk = 0; kk < 2; ++kk) {
        int kr = ni * 16 + c;
        int slot = (kk * 4 + g) ^ (kr & 7);
        kb[ni][kk] = *(const bf16x8*)&Ks[buf][kr * 64 + slot * 8];
      }
    f32x4 s[4];
    __builtin_amdgcn_s_setprio(1);
#pragma unroll
    for (int ni = 0; ni < 4; ++ni) {
      f32x4 a = {0.f, 0.f, 0.f, 0.f};
      a = __builtin_amdgcn_mfma_f32_16x16x32_bf16(kb[ni][0], qf[0], a, 0, 0, 0);
      a = __builtin_amdgcn_mfma_f32_16x16x32_bf16(kb[ni][1], qf[1], a, 0, 0, 0);
      s[ni] = a;
    }
    __builtin_amdgcn_s_setprio(0);

    // p = exp2(s); causal mask -> -inf -> 0 (only diag tile masks)
    const bool dumask = (kt == qt);
#pragma unroll
    for (int ni = 0; ni < 4; ++ni)
#pragma unroll
      for (int i = 0; i < 4; ++i) {
        float val = s[ni][i];
        if (dumask) {
          int key = j0 + ni * 16 + g * 4 + i;
          if (key > qrow0 + c) val = -3.0e38f;
        }
        s[ni][i] = __builtin_amdgcn_exp2f(val);
      }

    // In-register P fragment (fp16): storage slot b*32+g*8+q*4+i holds real
    // key (2q+b)*16+g*4+i = s[2q+b][i]. Matches V's storage permutation.
    u32x4 pa0 = { pkh(s[0][0], s[0][1]), pkh(s[0][2], s[0][3]),
                  pkh(s[2][0], s[2][1]), pkh(s[2][2], s[2][3]) };
    u32x4 pa1 = { pkh(s[1][0], s[1][1]), pkh(s[1][2], s[1][3]),
                  pkh(s[3][0], s[3][1]), pkh(s[3][2], s[3][3]) };
    f16x8 pa[2];
    pa[0] = __builtin_bit_cast(f16x8, pa0);
    pa[1] = __builtin_bit_cast(f16x8, pa1);

    // O += P @ V; l += P @ 1 (fp16 inputs, fp32 accum)
    f16x8 vb[4][2];
#pragma unroll
    for (int di = 0; di < 4; ++di)
#pragma unroll
      for (int kk = 0; kk < 2; ++kk) {
        int d = di * 16 + c;
        int slot = (kk * 4 + g) ^ (d & 7);
        vb[di][kk] = *(const f16x8*)&Vs[buf][d * 64 + slot * 8];
      }
    __builtin_amdgcn_s_setprio(1);
    ol = __builtin_amdgcn_mfma_f32_16x16x32_f16(pa[0], ones, ol, 0, 0, 0);
    ol = __builtin_amdgcn_mfma_f32_16x16x32_f16(pa[1], ones, ol, 0, 0, 0);
#pragma unroll
    for (int di = 0; di < 4; ++di) {
      o[di] = __builtin_amdgcn_mfma_f32_16x16x32_f16(pa[0], vb[di][0], o[di], 0, 0, 0);
      o[di] = __builtin_amdgcn_mfma_f32_16x16x32_f16(pa[1], vb[di][1], o[di], 0, 0, 0);
    }
    __builtin_amdgcn_s_setprio(0);
    buf ^= 1;
  }

  // epilogue: y[b, t, h*64 + d] = o / l   (o rows = q-rows g*4+i, cols = d)
#pragma unroll
  for (int i = 0; i < 4; ++i) {
    float inv = 1.f / ol[i];
    int t = qrow0 + g * 4 + i;
#pragma unroll
    for (int di = 0; di < 4; ++di) {
      int col = h * 64 + di * 16 + c;
      y[((size_t)b * 2048 + t) * 1024 + col] = f2bf(o[di][i] * inv);
    }
  }
}

// ---------------------------------------------------------------- launch
extern "C" void kernel_launch(void* const* d_in, const int* in_sizes, int n_in,
                              void* d_out, int out_size, void* d_ws, size_t ws_size,
                              hipStream_t stream) {
  // setup_inputs order: x, Wk, Wq, Wv, Wp
  const float* x  = (const float*)d_in[0];
  const float* Wk = (const float*)d_in[1];
  const float* Wq = (const float*)d_in[2];
  const float* Wv = (const float*)d_in[3];
  const float* Wp = (const float*)d_in[4];
  float* out = (float*)d_out;

  char* ws = (char*)d_ws;
  const size_t SZ_X = (size_t)4096 * 1024 * 2;  // 8 MiB per activation buffer
  const size_t SZ_W = (size_t)1024 * 1024 * 2;  // 2 MiB per weight
  u16* vb  = (u16*)(ws);                  // v [B,H,T,D] bf16; reused as y after transpose
  u16* qb  = (u16*)(ws + SZ_X);
  u16* kb  = (u16*)(ws + 2 * SZ_X);
  u16* vtb = (u16*)(ws + 3 * SZ_X);       // V^T fp16 [B,H,64,T]
  u16* wqb = (u16*)(ws + 4 * SZ_X);
  u16* wkb = (u16*)(ws + 4 * SZ_X + SZ_W);
  u16* wvb = (u16*)(ws + 4 * SZ_X + 2 * SZ_W);
  u16* wpb = (u16*)(ws + 4 * SZ_X + 3 * SZ_W);
  // total workspace: 40 MiB

  cvt_w4<<<dim3(1024, 4), 256, 0, stream>>>(Wq, Wk, Wv, Wp, wqb, wkb, wvb, wpb);

  proj_qkv<<<dim3(8, 32, 3), 256, 0, stream>>>(x, wqb, wkb, wvb, qb, kb, vb);

  transpose_v_kernel<<<dim3(32, 32), 256, 0, stream>>>(vb, vtb);

  u16* yb = vb;   // v [B,H,T,D] is dead after transpose
  attn_kernel<<<dim3(32, 32), 256, 0, stream>>>(qb, kb, vtb, yb);

  gemm_out<<<dim3(8, 64), 256, 0, stream>>>(yb, wpb, out);
}

// Round 15
// 110.497 us; speedup vs baseline: 1.0983x; 1.0595x over previous
//
#include <hip/hip_runtime.h>

typedef unsigned short u16;
typedef unsigned int u32;
typedef unsigned long long u64;
typedef __attribute__((ext_vector_type(8))) short bf16x8;
typedef __attribute__((ext_vector_type(8))) _Float16 f16x8;
typedef __attribute__((ext_vector_type(4))) float f32x4;
typedef __attribute__((ext_vector_type(4))) u32 u32x4;

#define GLOAD16(gp, lp) __builtin_amdgcn_global_load_lds( \
  (const __attribute__((address_space(1))) unsigned int*)(gp), \
  (__attribute__((address_space(3))) unsigned int*)(lp), 16, 0, 0)

__device__ __forceinline__ u16 f2bf(float f) {
  unsigned int u = __builtin_bit_cast(unsigned int, f);
  u += 0x7fffu + ((u >> 16) & 1u);   // RNE
  return (u16)(u >> 16);
}

// packed f32x2 -> bf16x2 (bit-op RNE; compiler schedules freely)
__device__ __forceinline__ u32 pk2(float a, float b) {
  return (u32)f2bf(a) | ((u32)f2bf(b) << 16);
}

// packed f32x2 -> f16x2 via hardware v_cvt_pkrtz_f16_f32 (single op)
__device__ __forceinline__ u32 pkh(float a, float b) {
  return __builtin_bit_cast(u32, __builtin_amdgcn_cvt_pkrtz(a, b));
}

// Counted-prefetch barrier: wait for the PREVIOUS iteration's staging (its
// latency was hidden under a full iteration of compute), then raw barrier.
// sched_barrier keeps the compiler from hoisting LDS reads above it.
__device__ __forceinline__ void wait_barrier() {
  asm volatile("s_waitcnt vmcnt(0)" ::: "memory");
  __builtin_amdgcn_s_barrier();
  __builtin_amdgcn_sched_barrier(0);
}

// ---------------------------------------------------------------- converts
// One launch for x + all 4 weights: grid 8192 blocks x 1024 elems.
__global__ __launch_bounds__(256) void cvt_all(
    const float* __restrict__ x,
    const float* __restrict__ w0, const float* __restrict__ w1,
    const float* __restrict__ w2, const float* __restrict__ w3,
    u16* __restrict__ ox, u16* __restrict__ o0, u16* __restrict__ o1,
    u16* __restrict__ o2, u16* __restrict__ o3) {
  int bid = blockIdx.x;
  const float* in; u16* out; size_t off;
  if (bid < 4096) {
    in = x; out = ox; off = (size_t)bid << 10;
  } else {
    int r = bid - 4096, z = r >> 10;
    in  = (z == 0) ? w0 : (z == 1) ? w1 : (z == 2) ? w2 : w3;
    out = (z == 0) ? o0 : (z == 1) ? o1 : (z == 2) ? o2 : o3;
    off = (size_t)(r & 1023) << 10;
  }
  size_t i = off + (size_t)threadIdx.x * 4;
  float4 f = *reinterpret_cast<const float4*>(in + i);
  u64 v = (u64)pk2(f.x, f.y) | ((u64)pk2(f.z, f.w) << 32);
  *reinterpret_cast<u64*>(out + i) = v;
}

// ---------------------------------------------------------------- GEMM (B^T)
// C[m,n] = sum_k A[m,k] * Bw[n,k]; Bw:[1024,1024] bf16.
// Tile (MI*32) x 128, BK=32, 4 waves (2x2). Counted-prefetch schedule.
template<int MODE, int MI>   // MODE 0: bf16 [B,H,T,D] (scaled); 1: fp32 [M,1024]
__device__ __forceinline__ void gemm_bt_body(
    const u16* __restrict__ A, const u16* __restrict__ Bw, void* __restrict__ Cout,
    int m0, int n0, float scale) {
  const int K = 1024;
  __shared__ __align__(16) u16 As[2][MI * 32 * 32];
  __shared__ __align__(16) u16 Bs[2][128 * 32];
  const int tid = threadIdx.x;
  const int lane = tid & 63, wid = tid >> 6;
  const int wr = wid >> 1, wc = wid & 1;
  const int g = lane >> 4, c = lane & 15;
  f32x4 acc[MI][4] = {};

  auto stage = [&](int buf, int k0) {
#pragma unroll
    for (int i = 0; i < MI / 2; ++i) {
      int idx = tid + i * 256;
      int row = idx >> 2, slot = idx & 3;
      int ss = slot ^ (row & 3);
      GLOAD16(A + (size_t)(m0 + row) * K + k0 + ss * 8, &As[buf][idx * 8]);
    }
#pragma unroll
    for (int i = 0; i < 2; ++i) {
      int idx = tid + i * 256;
      int row = idx >> 2, slot = idx & 3;
      int ss = slot ^ (row & 3);
      GLOAD16(Bw + (size_t)(n0 + row) * K + k0 + ss * 8, &Bs[buf][idx * 8]);
    }
  };

  stage(0, 0);
  int buf = 0;
#pragma unroll 1
  for (int kt = 0; kt < 32; ++kt) {
    wait_barrier();
    if (kt + 1 < 32) stage(buf ^ 1, (kt + 1) * 32);
    bf16x8 af[MI], bfr[4];
#pragma unroll
    for (int mi = 0; mi < MI; ++mi) {
      int row = wr * (MI * 16) + mi * 16 + c;
      int slot = g ^ (row & 3);
      af[mi] = *(const bf16x8*)&As[buf][row * 32 + slot * 8];
    }
#pragma unroll
    for (int ni = 0; ni < 4; ++ni) {
      int row = wc * 64 + ni * 16 + c;
      int slot = g ^ (row & 3);
      bfr[ni] = *(const bf16x8*)&Bs[buf][row * 32 + slot * 8];
    }
    __builtin_amdgcn_s_setprio(1);
#pragma unroll
    for (int mi = 0; mi < MI; ++mi)
#pragma unroll
      for (int ni = 0; ni < 4; ++ni)
        acc[mi][ni] = __builtin_amdgcn_mfma_f32_16x16x32_bf16(af[mi], bfr[ni], acc[mi][ni], 0, 0, 0);
    __builtin_amdgcn_s_setprio(0);
    buf ^= 1;
  }

#pragma unroll
  for (int mi = 0; mi < MI; ++mi)
#pragma unroll
    for (int ni = 0; ni < 4; ++ni)
#pragma unroll
      for (int i = 0; i < 4; ++i) {
        int m = m0 + wr * (MI * 16) + mi * 16 + g * 4 + i;
        int n = n0 + wc * 64 + ni * 16 + c;
        float v = acc[mi][ni][i];
        if (MODE == 0) {
          int b = m >> 11, t = m & 2047, h = n >> 6, d = n & 63;
          ((u16*)Cout)[(((size_t)b * 16 + h) * 2048 + t) * 64 + d] = f2bf(v * scale);
        } else {
          ((float*)Cout)[(size_t)m * 1024 + n] = v;
        }
      }
}

// Q is pre-scaled by (1/sqrt(D)) * log2(e) so attn scores are in log2 domain.
#define QSCALE 0.1803368801111204f

__global__ __launch_bounds__(256, 3) void proj_qkv(
    const u16* __restrict__ xb, const u16* __restrict__ wq, const u16* __restrict__ wk,
    const u16* __restrict__ wv, u16* __restrict__ q, u16* __restrict__ k, u16* __restrict__ v) {
  int z = blockIdx.z;
  const u16* W = (z == 0) ? wq : (z == 1) ? wk : wv;
  u16* O = (z == 0) ? q : (z == 1) ? k : v;
  float scale = (z == 0) ? QSCALE : 1.0f;
  gemm_bt_body<0, 4>(xb, W, O, blockIdx.y * 128, blockIdx.x * 128, scale);
}

// 64-row tiles: grid (8, 64) = 512 blocks -> 2 blocks/CU.
__global__ __launch_bounds__(256, 2) void gemm_out(
    const u16* __restrict__ y, const u16* __restrict__ wp, float* __restrict__ out) {
  gemm_bt_body<1, 2>(y, wp, out, blockIdx.y * 64, blockIdx.x * 128, 1.0f);
}

// ---------------------------------------------------------------- V transpose
// v [B,H,T,64] bf16 -> vt [B,H,64,T] FP16, with per-64-tile key permutation:
// storage slot j holds real key real(j) = (2*((j>>2)&1) + (j>>5))*16
// + ((j>>3)&3)*4 + (j&3). This matches the in-register P fragment produced by
// the swapped QK^T in attn, so PV contracts correctly.
__global__ __launch_bounds__(256) void transpose_v_kernel(
    const u16* __restrict__ v, u16* __restrict__ vt) {
  __shared__ u16 tile[64][65];
  int bh = blockIdx.y, t0 = blockIdx.x * 64;
  const u16* src = v + ((size_t)bh * 2048 + t0) * 64;
  u16* dst = vt + (size_t)bh * 64 * 2048 + t0;
  int tid = threadIdx.x;
#pragma unroll
  for (int i = 0; i < 16; ++i) {
    int idx = tid + i * 256;
    tile[idx >> 6][idx & 63] = src[idx];
  }
  __syncthreads();
#pragma unroll
  for (int i = 0; i < 16; ++i) {
    int idx = tid + i * 256;
    int d = idx >> 6, j = idx & 63;
    int t = (((((j >> 2) & 1) << 1) | (j >> 5)) << 4) | (((j >> 3) & 3) << 2) | (j & 3);
    float f = __builtin_bit_cast(float, (u32)tile[t][d] << 16);
    _Float16 hh = (_Float16)f;
    dst[(size_t)d * 2048 + j] = __builtin_bit_cast(u16, hh);
  }
}

// ---------------------------------------------------------------- flash attention
// grid (32 bh, 32): 64 q-rows/block (4 waves x 16), KVBLK=64, 32KB LDS,
// 4 blocks/CU. qt remap balances per-CU work: co-resident blocks (linear ids
// differing by 256 -> same CU) have y in {o,o+8,o+16,o+24}; qt(y) =
// {o, 31-o, 8+o, 23-o} makes every CU's iteration sum exactly 66.
// SWAPPED QK^T: mfma(K,Q) -> lane (g,c) holds 16 scores for q-row (qrow0+c),
// keys ni*16+g*4+i. With the matching V storage permutation, the PV A-frag
// is packed fully IN REGISTERS (8 pkh) -> no P LDS round-trip at all.
// FIXED-BASE softmax: p = exp2(s) directly (log2-domain scores, bounded;
// fp32 exp2 headroom ~2^116). Row-sums via MFMA vs all-ones. Counted-prefetch
// barrier at loop top hides staging latency under a full iteration.
__global__ __launch_bounds__(256, 4) void attn_kernel(
    const u16* __restrict__ q, const u16* __restrict__ kg,
    const u16* __restrict__ vt, u16* __restrict__ y) {
  const int T = 2048;
  __shared__ __align__(16) u16 Ks[2][64 * 64];   // [key][d] bf16
  __shared__ __align__(16) u16 Vs[2][64 * 64];   // [d][key-slot] fp16 (perm'd)
  const int tid = threadIdx.x, lane = tid & 63, w = tid >> 6;
  const int g = lane >> 4, c = lane & 15;
  const int bh = blockIdx.x;
  const int yy = blockIdx.y, m8 = yy >> 3, o8 = yy & 7;
  const int qt = (m8 == 0) ? o8 : (m8 == 1) ? 31 - o8 : (m8 == 2) ? 8 + o8 : 23 - o8;
  const u16* Q = q + (size_t)bh * T * 64;
  const u16* K = kg + (size_t)bh * T * 64;
  const u16* V = vt + (size_t)bh * 64 * T;
  const int b = bh >> 4, h = bh & 15;
  const int qrow0 = qt * 64 + w * 16;

  f16x8 ones;
#pragma unroll
  for (int j = 0; j < 8; ++j) ones[j] = (_Float16)1.0f;

  auto stage = [&](int bb, int j0) {
#pragma unroll
    for (int i = 0; i < 2; ++i) {
      int idx = tid + i * 256;
      int row = idx >> 3, slot = idx & 7;
      int ss = slot ^ (row & 7);
      GLOAD16(K + (size_t)(j0 + row) * 64 + ss * 8, &Ks[bb][idx * 8]);
      GLOAD16(V + (size_t)row * T + j0 + ss * 8, &Vs[bb][idx * 8]);
    }
  };

  bf16x8 qf[2];
#pragma unroll
  for (int kk = 0; kk < 2; ++kk)
    qf[kk] = *(const bf16x8*)&Q[(size_t)(qrow0 + c) * 64 + kk * 32 + g * 8];

  f32x4 o[4] = {};
  f32x4 ol = {};   // row-sums (every column identical)

  const int nkt = qt + 1;
  stage(0, 0);
  int buf = 0;
#pragma unroll 1
  for (int kt = 0; kt < nkt; ++kt) {
    const int j0 = kt * 64;
    wait_barrier();
    if (kt + 1 < nkt) stage(buf ^ 1, j0 + 64);

    // S^T = K Q^T: s[ni][i] = S[q-row qrow0+c][key j0 + ni*16 + g*4 + i]
    bf16x8 kb[4][2];
#pragma unroll
    for (int ni = 0; ni < 4; ++ni)
#pragma unroll
      for (int kk = 0; kk < 2; ++kk) {
        int kr = ni * 16 + c;
        int slot = (kk * 4 + g) ^ (kr & 7);
        kb[ni][kk] = *(const bf16x8*)&Ks[buf][kr * 64 + slot * 8];
      }
    f32x4 s[4];
    __builtin_amdgcn_s_setprio(1);
#pragma unroll
    for (int ni = 0; ni < 4; ++ni) {
      f32x4 a = {0.f, 0.f, 0.f, 0.f};
      a = __builtin_amdgcn_mfma_f32_16x16x32_bf16(kb[ni][0], qf[0], a, 0, 0, 0);
      a = __builtin_amdgcn_mfma_f32_16x16x32_bf16(kb[ni][1], qf[1], a, 0, 0, 0);
      s[ni] = a;
    }
    __builtin_amdgcn_s_setprio(0);

    // p = exp2(s); causal mask -> -inf -> 0 (only diag tile masks)
    const bool dumask = (kt == qt);
#pragma unroll
    for (int ni = 0; ni < 4; ++ni)
#pragma unroll
      for (int i = 0; i < 4; ++i) {
        float val = s[ni][i];
        if (dumask) {
          int key = j0 + ni * 16 + g * 4 + i;
          if (key > qrow0 + c) val = -3.0e38f;
        }
        s[ni][i] = __builtin_amdgcn_exp2f(val);
      }

    // In-register P fragment (fp16): storage slot b*32+g*8+q*4+i holds real
    // key (2q+b)*16+g*4+i = s[2q+b][i]. Matches V's storage permutation.
    u32x4 pa0 = { pkh(s[0][0], s[0][1]), pkh(s[0][2], s[0][3]),
                  pkh(s[2][0], s[2][1]), pkh(s[2][2], s[2][3]) };
    u32x4 pa1 = { pkh(s[1][0], s[1][1]), pkh(s[1][2], s[1][3]),
                  pkh(s[3][0], s[3][1]), pkh(s[3][2], s[3][3]) };
    f16x8 pa[2];
    pa[0] = __builtin_bit_cast(f16x8, pa0);
    pa[1] = __builtin_bit_cast(f16x8, pa1);

    // O += P @ V; l += P @ 1 (fp16 inputs, fp32 accum)
    f16x8 vb[4][2];
#pragma unroll
    for (int di = 0; di < 4; ++di)
#pragma unroll
      for (int kk = 0; kk < 2; ++kk) {
        int d = di * 16 + c;
        int slot = (kk * 4 + g) ^ (d & 7);
        vb[di][kk] = *(const f16x8*)&Vs[buf][d * 64 + slot * 8];
      }
    __builtin_amdgcn_s_setprio(1);
    ol = __builtin_amdgcn_mfma_f32_16x16x32_f16(pa[0], ones, ol, 0, 0, 0);
    ol = __builtin_amdgcn_mfma_f32_16x16x32_f16(pa[1], ones, ol, 0, 0, 0);
#pragma unroll
    for (int di = 0; di < 4; ++di) {
      o[di] = __builtin_amdgcn_mfma_f32_16x16x32_f16(pa[0], vb[di][0], o[di], 0, 0, 0);
      o[di] = __builtin_amdgcn_mfma_f32_16x16x32_f16(pa[1], vb[di][1], o[di], 0, 0, 0);
    }
    __builtin_amdgcn_s_setprio(0);
    buf ^= 1;
  }

  // epilogue: y[b, t, h*64 + d] = o / l   (o rows = q-rows g*4+i, cols = d)
#pragma unroll
  for (int i = 0; i < 4; ++i) {
    float inv = 1.f / ol[i];
    int t = qrow0 + g * 4 + i;
#pragma unroll
    for (int di = 0; di < 4; ++di) {
      int col = h * 64 + di * 16 + c;
      y[((size_t)b * 2048 + t) * 1024 + col] = f2bf(o[di][i] * inv);
    }
  }
}

// ---------------------------------------------------------------- launch
extern "C" void kernel_launch(void* const* d_in, const int* in_sizes, int n_in,
                              void* d_out, int out_size, void* d_ws, size_t ws_size,
                              hipStream_t stream) {
  // setup_inputs order: x, Wk, Wq, Wv, Wp
  const float* x  = (const float*)d_in[0];
  const float* Wk = (const float*)d_in[1];
  const float* Wq = (const float*)d_in[2];
  const float* Wv = (const float*)d_in[3];
  const float* Wp = (const float*)d_in[4];
  float* out = (float*)d_out;

  char* ws = (char*)d_ws;
  const size_t SZ_X = (size_t)4096 * 1024 * 2;  // 8 MiB (x_bf16 / q / k / v each)
  const size_t SZ_W = (size_t)1024 * 1024 * 2;  // 2 MiB per weight
  u16* xb  = (u16*)(ws);                  // x bf16; reused as vt (fp16) after proj
  u16* qb  = (u16*)(ws + SZ_X);
  u16* kb  = (u16*)(ws + 2 * SZ_X);
  u16* vb  = (u16*)(ws + 3 * SZ_X);       // v [B,H,T,D]; reused as y after transpose
  u16* wqb = (u16*)(ws + 4 * SZ_X);
  u16* wkb = (u16*)(ws + 4 * SZ_X + SZ_W);
  u16* wvb = (u16*)(ws + 4 * SZ_X + 2 * SZ_W);
  u16* wpb = (u16*)(ws + 4 * SZ_X + 3 * SZ_W);
  // total workspace: 40 MiB

  cvt_all<<<8192, 256, 0, stream>>>(x, Wq, Wk, Wv, Wp, xb, wqb, wkb, wvb, wpb);

  proj_qkv<<<dim3(8, 32, 3), 256, 0, stream>>>(xb, wqb, wkb, wvb, qb, kb, vb);

  u16* vtb = xb;  // x_bf16 is dead after projections
  transpose_v_kernel<<<dim3(32, 32), 256, 0, stream>>>(vb, vtb);

  u16* yb = vb;   // v [B,H,T,D] is dead after transpose
  attn_kernel<<<dim3(32, 32), 256, 0, stream>>>(qb, kb, vtb, yb);

  gemm_out<<<dim3(8, 64), 256, 0, stream>>>(yb, wpb, out);
}

// Round 16
// 108.897 us; speedup vs baseline: 1.1144x; 1.0147x over previous
//
#include <hip/hip_runtime.h>

typedef unsigned short u16;
typedef unsigned int u32;
typedef unsigned long long u64;
typedef __attribute__((ext_vector_type(8))) short bf16x8;
typedef __attribute__((ext_vector_type(8))) _Float16 f16x8;
typedef __attribute__((ext_vector_type(4))) float f32x4;
typedef __attribute__((ext_vector_type(4))) u32 u32x4;

#define GLOAD16(gp, lp) __builtin_amdgcn_global_load_lds( \
  (const __attribute__((address_space(1))) unsigned int*)(gp), \
  (__attribute__((address_space(3))) unsigned int*)(lp), 16, 0, 0)

__device__ __forceinline__ u16 f2bf(float f) {
  unsigned int u = __builtin_bit_cast(unsigned int, f);
  u += 0x7fffu + ((u >> 16) & 1u);   // RNE
  return (u16)(u >> 16);
}

// packed f32x2 -> bf16x2 (bit-op RNE; compiler schedules freely)
__device__ __forceinline__ u32 pk2(float a, float b) {
  return (u32)f2bf(a) | ((u32)f2bf(b) << 16);
}

// packed f32x2 -> f16x2 via hardware v_cvt_pkrtz_f16_f32 (single op)
__device__ __forceinline__ u32 pkh(float a, float b) {
  return __builtin_bit_cast(u32, __builtin_amdgcn_cvt_pkrtz(a, b));
}

// Counted-prefetch barrier: wait for the PREVIOUS iteration's staging (its
// latency was hidden under a full iteration of compute), then raw barrier.
// sched_barrier keeps the compiler from hoisting LDS reads above it.
__device__ __forceinline__ void wait_barrier() {
  asm volatile("s_waitcnt vmcnt(0)" ::: "memory");
  __builtin_amdgcn_s_barrier();
  __builtin_amdgcn_sched_barrier(0);
}

// ---------------------------------------------------------------- converts
// One launch for x + all 4 weights: grid 8192 blocks x 1024 elems.
__global__ __launch_bounds__(256) void cvt_all(
    const float* __restrict__ x,
    const float* __restrict__ w0, const float* __restrict__ w1,
    const float* __restrict__ w2, const float* __restrict__ w3,
    u16* __restrict__ ox, u16* __restrict__ o0, u16* __restrict__ o1,
    u16* __restrict__ o2, u16* __restrict__ o3) {
  int bid = blockIdx.x;
  const float* in; u16* out; size_t off;
  if (bid < 4096) {
    in = x; out = ox; off = (size_t)bid << 10;
  } else {
    int r = bid - 4096, z = r >> 10;
    in  = (z == 0) ? w0 : (z == 1) ? w1 : (z == 2) ? w2 : w3;
    out = (z == 0) ? o0 : (z == 1) ? o1 : (z == 2) ? o2 : o3;
    off = (size_t)(r & 1023) << 10;
  }
  size_t i = off + (size_t)threadIdx.x * 4;
  float4 f = *reinterpret_cast<const float4*>(in + i);
  u64 v = (u64)pk2(f.x, f.y) | ((u64)pk2(f.z, f.w) << 32);
  *reinterpret_cast<u64*>(out + i) = v;
}

// ---------------------------------------------------------------- GEMM (B^T)
// C[m,n] = sum_k A[m,k] * Bw[n,k]; Bw:[1024,1024] bf16.
// Tile MT x NT, BK=32, 4 waves (2x2). Counted-prefetch schedule:
// {wait+barrier; stage(next); compute(cur)} -> staging latency hidden under
// a full iteration of compute.
template<int MODE, int MT, int NT>  // MODE 0: bf16 [B,H,T,D] (scaled); 1: fp32 [M,1024]
__device__ __forceinline__ void gemm_bt_body(
    const u16* __restrict__ A, const u16* __restrict__ Bw, void* __restrict__ Cout,
    int m0, int n0, float scale) {
  const int K = 1024;
  __shared__ __align__(16) u16 As[2][MT * 32];
  __shared__ __align__(16) u16 Bs[2][NT * 32];
  const int tid = threadIdx.x;
  const int lane = tid & 63, wid = tid >> 6;
  const int wr = wid >> 1, wc = wid & 1;
  const int g = lane >> 4, c = lane & 15;
  f32x4 acc[MT / 32][NT / 32] = {};

  auto stage = [&](int buf, int k0) {
#pragma unroll
    for (int i = 0; i < MT / 64; ++i) {
      int idx = tid + i * 256;
      int row = idx >> 2, slot = idx & 3;
      int ss = slot ^ (row & 3);
      GLOAD16(A + (size_t)(m0 + row) * K + k0 + ss * 8, &As[buf][idx * 8]);
    }
#pragma unroll
    for (int i = 0; i < NT / 64; ++i) {
      int idx = tid + i * 256;
      int row = idx >> 2, slot = idx & 3;
      int ss = slot ^ (row & 3);
      GLOAD16(Bw + (size_t)(n0 + row) * K + k0 + ss * 8, &Bs[buf][idx * 8]);
    }
  };

  stage(0, 0);
  int buf = 0;
#pragma unroll 1
  for (int kt = 0; kt < 32; ++kt) {
    wait_barrier();
    if (kt + 1 < 32) stage(buf ^ 1, (kt + 1) * 32);
    bf16x8 af[MT / 32], bfr[NT / 32];
#pragma unroll
    for (int mi = 0; mi < MT / 32; ++mi) {
      int row = wr * (MT / 2) + mi * 16 + c;
      int slot = g ^ (row & 3);
      af[mi] = *(const bf16x8*)&As[buf][row * 32 + slot * 8];
    }
#pragma unroll
    for (int ni = 0; ni < NT / 32; ++ni) {
      int row = wc * (NT / 2) + ni * 16 + c;
      int slot = g ^ (row & 3);
      bfr[ni] = *(const bf16x8*)&Bs[buf][row * 32 + slot * 8];
    }
    __builtin_amdgcn_s_setprio(1);
#pragma unroll
    for (int mi = 0; mi < MT / 32; ++mi)
#pragma unroll
      for (int ni = 0; ni < NT / 32; ++ni)
        acc[mi][ni] = __builtin_amdgcn_mfma_f32_16x16x32_bf16(af[mi], bfr[ni], acc[mi][ni], 0, 0, 0);
    __builtin_amdgcn_s_setprio(0);
    buf ^= 1;
  }

#pragma unroll
  for (int mi = 0; mi < MT / 32; ++mi)
#pragma unroll
    for (int ni = 0; ni < NT / 32; ++ni)
#pragma unroll
      for (int i = 0; i < 4; ++i) {
        int m = m0 + wr * (MT / 2) + mi * 16 + g * 4 + i;
        int n = n0 + wc * (NT / 2) + ni * 16 + c;
        float v = acc[mi][ni][i];
        if (MODE == 0) {
          int b = m >> 11, t = m & 2047, h = n >> 6, d = n & 63;
          ((u16*)Cout)[(((size_t)b * 16 + h) * 2048 + t) * 64 + d] = f2bf(v * scale);
        } else {
          ((float*)Cout)[(size_t)m * 1024 + n] = v;
        }
      }
}

// Q is pre-scaled by (1/sqrt(D)) * log2(e) so attn scores are in log2 domain.
#define QSCALE 0.1803368801111204f

__global__ __launch_bounds__(256, 3) void proj_qkv(
    const u16* __restrict__ xb, const u16* __restrict__ wq, const u16* __restrict__ wk,
    const u16* __restrict__ wv, u16* __restrict__ q, u16* __restrict__ k, u16* __restrict__ v) {
  int z = blockIdx.z;
  const u16* W = (z == 0) ? wq : (z == 1) ? wk : wv;
  u16* O = (z == 0) ? q : (z == 1) ? k : v;
  float scale = (z == 0) ? QSCALE : 1.0f;
  gemm_bt_body<0, 128, 128>(xb, W, O, blockIdx.y * 128, blockIdx.x * 128, scale);
}

// 64x64 tiles: grid (16, 64) = 1024 blocks -> 4 blocks/CU (TLP over density,
// per the round-7 lesson; at 64x128/512-block this kernel ran 573 TF vs
// proj's 920 TF on the same inner loop).
__global__ __launch_bounds__(256, 4) void gemm_out(
    const u16* __restrict__ y, const u16* __restrict__ wp, float* __restrict__ out) {
  gemm_bt_body<1, 64, 64>(y, wp, out, blockIdx.y * 64, blockIdx.x * 64, 1.0f);
}

// ---------------------------------------------------------------- V transpose
// v [B,H,T,64] bf16 -> vt [B,H,64,T] FP16, with per-64-tile key permutation:
// storage slot j holds real key real(j) = (2*((j>>2)&1) + (j>>5))*16
// + ((j>>3)&3)*4 + (j&3). This matches the in-register P fragment produced by
// the swapped QK^T in attn, so PV contracts correctly.
__global__ __launch_bounds__(256) void transpose_v_kernel(
    const u16* __restrict__ v, u16* __restrict__ vt) {
  __shared__ u16 tile[64][65];
  int bh = blockIdx.y, t0 = blockIdx.x * 64;
  const u16* src = v + ((size_t)bh * 2048 + t0) * 64;
  u16* dst = vt + (size_t)bh * 64 * 2048 + t0;
  int tid = threadIdx.x;
#pragma unroll
  for (int i = 0; i < 16; ++i) {
    int idx = tid + i * 256;
    tile[idx >> 6][idx & 63] = src[idx];
  }
  __syncthreads();
#pragma unroll
  for (int i = 0; i < 16; ++i) {
    int idx = tid + i * 256;
    int d = idx >> 6, j = idx & 63;
    int t = (((((j >> 2) & 1) << 1) | (j >> 5)) << 4) | (((j >> 3) & 3) << 2) | (j & 3);
    float f = __builtin_bit_cast(float, (u32)tile[t][d] << 16);
    _Float16 hh = (_Float16)f;
    dst[(size_t)d * 2048 + j] = __builtin_bit_cast(u16, hh);
  }
}

// ---------------------------------------------------------------- flash attention
// grid (32 bh, 32): 64 q-rows/block (4 waves x 16), KVBLK=64, 32KB LDS,
// 4 blocks/CU. qt remap balances per-CU work: co-resident blocks (linear ids
// differing by 256 -> same CU) have y in {o,o+8,o+16,o+24}; qt(y) =
// {o, 31-o, 8+o, 23-o} makes every CU's iteration sum exactly 66.
// SWAPPED QK^T: mfma(K,Q) -> lane (g,c) holds 16 scores for q-row (qrow0+c),
// keys ni*16+g*4+i. With the matching V storage permutation, the PV A-frag
// is packed fully IN REGISTERS (8 pkh) -> no P LDS round-trip at all.
// FIXED-BASE softmax: p = exp2(s) directly (log2-domain scores, bounded;
// fp32 exp2 headroom ~2^116). Row-sums via MFMA vs all-ones. Counted-prefetch
// barrier at loop top hides staging latency under a full iteration.
__global__ __launch_bounds__(256, 4) void attn_kernel(
    const u16* __restrict__ q, const u16* __restrict__ kg,
    const u16* __restrict__ vt, u16* __restrict__ y) {
  const int T = 2048;
  __shared__ __align__(16) u16 Ks[2][64 * 64];   // [key][d] bf16
  __shared__ __align__(16) u16 Vs[2][64 * 64];   // [d][key-slot] fp16 (perm'd)
  const int tid = threadIdx.x, lane = tid & 63, w = tid >> 6;
  const int g = lane >> 4, c = lane & 15;
  const int bh = blockIdx.x;
  const int yy = blockIdx.y, m8 = yy >> 3, o8 = yy & 7;
  const int qt = (m8 == 0) ? o8 : (m8 == 1) ? 31 - o8 : (m8 == 2) ? 8 + o8 : 23 - o8;
  const u16* Q = q + (size_t)bh * T * 64;
  const u16* K = kg + (size_t)bh * T * 64;
  const u16* V = vt + (size_t)bh * 64 * T;
  const int b = bh >> 4, h = bh & 15;
  const int qrow0 = qt * 64 + w * 16;

  f16x8 ones;
#pragma unroll
  for (int j = 0; j < 8; ++j) ones[j] = (_Float16)1.0f;

  auto stage = [&](int bb, int j0) {
#pragma unroll
    for (int i = 0; i < 2; ++i) {
      int idx = tid + i * 256;
      int row = idx >> 3, slot = idx & 7;
      int ss = slot ^ (row & 7);
      GLOAD16(K + (size_t)(j0 + row) * 64 + ss * 8, &Ks[bb][idx * 8]);
      GLOAD16(V + (size_t)row * T + j0 + ss * 8, &Vs[bb][idx * 8]);
    }
  };

  bf16x8 qf[2];
#pragma unroll
  for (int kk = 0; kk < 2; ++kk)
    qf[kk] = *(const bf16x8*)&Q[(size_t)(qrow0 + c) * 64 + kk * 32 + g * 8];

  f32x4 o[4] = {};
  f32x4 ol = {};   // row-sums (every column identical)

  const int nkt = qt + 1;
  stage(0, 0);
  int buf = 0;
#pragma unroll 1
  for (int kt = 0; kt < nkt; ++kt) {
    const int j0 = kt * 64;
    wait_barrier();
    if (kt + 1 < nkt) stage(buf ^ 1, j0 + 64);

    // S^T = K Q^T: s[ni][i] = S[q-row qrow0+c][key j0 + ni*16 + g*4 + i]
    bf16x8 kb[4][2];
#pragma unroll
    for (int ni = 0; ni < 4; ++ni)
#pragma unroll
      for (int kk = 0; kk < 2; ++kk) {
        int kr = ni * 16 + c;
        int slot = (kk * 4 + g) ^ (kr & 7);
        kb[ni][kk] = *(const bf16x8*)&Ks[buf][kr * 64 + slot * 8];
      }
    f32x4 s[4];
    __builtin_amdgcn_s_setprio(1);
#pragma unroll
    for (int ni = 0; ni < 4; ++ni) {
      f32x4 a = {0.f, 0.f, 0.f, 0.f};
      a = __builtin_amdgcn_mfma_f32_16x16x32_bf16(kb[ni][0], qf[0], a, 0, 0, 0);
      a = __builtin_amdgcn_mfma_f32_16x16x32_bf16(kb[ni][1], qf[1], a, 0, 0, 0);
      s[ni] = a;
    }
    __builtin_amdgcn_s_setprio(0);

    // p = exp2(s); causal mask -> -inf -> 0 (only diag tile masks)
    const bool dumask = (kt == qt);
#pragma unroll
    for (int ni = 0; ni < 4; ++ni)
#pragma unroll
      for (int i = 0; i < 4; ++i) {
        float val = s[ni][i];
        if (dumask) {
          int key = j0 + ni * 16 + g * 4 + i;
          if (key > qrow0 + c) val = -3.0e38f;
        }
        s[ni][i] = __builtin_amdgcn_exp2f(val);
      }

    // In-register P fragment (fp16): storage slot b*32+g*8+q*4+i holds real
    // key (2q+b)*16+g*4+i = s[2q+b][i]. Matches V's storage permutation.
    u32x4 pa0 = { pkh(s[0][0], s[0][1]), pkh(s[0][2], s[0][3]),
                  pkh(s[2][0], s[2][1]), pkh(s[2][2], s[2][3]) };
    u32x4 pa1 = { pkh(s[1][0], s[1][1]), pkh(s[1][2], s[1][3]),
                  pkh(s[3][0], s[3][1]), pkh(s[3][2], s[3][3]) };
    f16x8 pa[2];
    pa[0] = __builtin_bit_cast(f16x8, pa0);
    pa[1] = __builtin_bit_cast(f16x8, pa1);

    // O += P @ V; l += P @ 1 (fp16 inputs, fp32 accum)
    f16x8 vb[4][2];
#pragma unroll
    for (int di = 0; di < 4; ++di)
#pragma unroll
      for (int kk = 0; kk < 2; ++kk) {
        int d = di * 16 + c;
        int slot = (kk * 4 + g) ^ (d & 7);
        vb[di][kk] = *(const f16x8*)&Vs[buf][d * 64 + slot * 8];
      }
    __builtin_amdgcn_s_setprio(1);
    ol = __builtin_amdgcn_mfma_f32_16x16x32_f16(pa[0], ones, ol, 0, 0, 0);
    ol = __builtin_amdgcn_mfma_f32_16x16x32_f16(pa[1], ones, ol, 0, 0, 0);
#pragma unroll
    for (int di = 0; di < 4; ++di) {
      o[di] = __builtin_amdgcn_mfma_f32_16x16x32_f16(pa[0], vb[di][0], o[di], 0, 0, 0);
      o[di] = __builtin_amdgcn_mfma_f32_16x16x32_f16(pa[1], vb[di][1], o[di], 0, 0, 0);
    }
    __builtin_amdgcn_s_setprio(0);
    buf ^= 1;
  }

  // epilogue: y[b, t, h*64 + d] = o / l   (o rows = q-rows g*4+i, cols = d)
#pragma unroll
  for (int i = 0; i < 4; ++i) {
    float inv = 1.f / ol[i];
    int t = qrow0 + g * 4 + i;
#pragma unroll
    for (int di = 0; di < 4; ++di) {
      int col = h * 64 + di * 16 + c;
      y[((size_t)b * 2048 + t) * 1024 + col] = f2bf(o[di][i] * inv);
    }
  }
}

// ---------------------------------------------------------------- launch
extern "C" void kernel_launch(void* const* d_in, const int* in_sizes, int n_in,
                              void* d_out, int out_size, void* d_ws, size_t ws_size,
                              hipStream_t stream) {
  // setup_inputs order: x, Wk, Wq, Wv, Wp
  const float* x  = (const float*)d_in[0];
  const float* Wk = (const float*)d_in[1];
  const float* Wq = (const float*)d_in[2];
  const float* Wv = (const float*)d_in[3];
  const float* Wp = (const float*)d_in[4];
  float* out = (float*)d_out;

  char* ws = (char*)d_ws;
  const size_t SZ_X = (size_t)4096 * 1024 * 2;  // 8 MiB (x_bf16 / q / k / v each)
  const size_t SZ_W = (size_t)1024 * 1024 * 2;  // 2 MiB per weight
  u16* xb  = (u16*)(ws);                  // x bf16; reused as vt (fp16) after proj
  u16* qb  = (u16*)(ws + SZ_X);
  u16* kb  = (u16*)(ws + 2 * SZ_X);
  u16* vb  = (u16*)(ws + 3 * SZ_X);       // v [B,H,T,D]; reused as y after transpose
  u16* wqb = (u16*)(ws + 4 * SZ_X);
  u16* wkb = (u16*)(ws + 4 * SZ_X + SZ_W);
  u16* wvb = (u16*)(ws + 4 * SZ_X + 2 * SZ_W);
  u16* wpb = (u16*)(ws + 4 * SZ_X + 3 * SZ_W);
  // total workspace: 40 MiB

  cvt_all<<<8192, 256, 0, stream>>>(x, Wq, Wk, Wv, Wp, xb, wqb, wkb, wvb, wpb);

  proj_qkv<<<dim3(8, 32, 3), 256, 0, stream>>>(xb, wqb, wkb, wvb, qb, kb, vb);

  u16* vtb = xb;  // x_bf16 is dead after projections
  transpose_v_kernel<<<dim3(32, 32), 256, 0, stream>>>(vb, vtb);

  u16* yb = vb;   // v [B,H,T,D] is dead after transpose
  attn_kernel<<<dim3(32, 32), 256, 0, stream>>>(qb, kb, vtb, yb);

  gemm_out<<<dim3(16, 64), 256, 0, stream>>>(yb, wpb, out);
}